// Round 4
// baseline (140.606 us; speedup 1.0000x reference)
//
#include <hip/hip_runtime.h>

// Problem constants (from reference setup_inputs)
#define N_  16
#define C_  64
#define H_  128
#define W_  128
#define HO_ 64
#define WO_ 64
#define CO_ 18   // G*K*K = 2*3*3

__global__ void pasa_fused(const float* __restrict__ x,
                           const float* __restrict__ cw,
                           const float* __restrict__ gamma,
                           const float* __restrict__ beta,
                           const float* __restrict__ mean,
                           const float* __restrict__ var,
                           float* __restrict__ out)
{
    const int tid = threadIdx.x;
    const int wo  = tid & 63;               // 0..63 output col
    const int ho  = (blockIdx.x << 2) | (tid >> 6); // 0..63 output row
    const int n   = blockIdx.y;

    // 3x3 window at input position (2*ho, 2*wo), reflect pad=1.
    // Only index -1 can occur (2*ho+1 <= 127); reflect(-1) = 1.
    int r0 = 2*ho - 1; if (r0 < 0) r0 = 1;
    const int r1 = 2*ho, r2 = 2*ho + 1;
    int c0 = 2*wo - 1; if (c0 < 0) c0 = 1;
    const int c1 = 2*wo, c2 = 2*wo + 1;

    const float* __restrict__ xn = x + (size_t)n * (C_*H_*W_);

    float sig[CO_];
#pragma unroll
    for (int o = 0; o < CO_; ++o) sig[o] = 0.f;

    // Pass 1: conv over all 64 channels -> 18 logits.
    // Weight indices are uniform (affine in c + constants) -> scalar loads.
#pragma unroll 4
    for (int c = 0; c < C_; ++c) {
        const float* __restrict__ xc = xn + c * (H_*W_);
        const float w0 = xc[r0*W_ + c0];
        const float w1 = xc[r0*W_ + c1];
        const float w2 = xc[r0*W_ + c2];
        const float w3 = xc[r1*W_ + c0];
        const float w4 = xc[r1*W_ + c1];
        const float w5 = xc[r1*W_ + c2];
        const float w6 = xc[r2*W_ + c0];
        const float w7 = xc[r2*W_ + c1];
        const float w8 = xc[r2*W_ + c2];
        const float* __restrict__ wc = cw + c * 9;
#pragma unroll
        for (int o = 0; o < CO_; ++o) {
            const float* __restrict__ wp = wc + o * 576; // co-stride = 64*9
            float a = sig[o];
            a = fmaf(w0, wp[0], a);
            a = fmaf(w1, wp[1], a);
            a = fmaf(w2, wp[2], a);
            a = fmaf(w3, wp[3], a);
            a = fmaf(w4, wp[4], a);
            a = fmaf(w5, wp[5], a);
            a = fmaf(w6, wp[6], a);
            a = fmaf(w7, wp[7], a);
            a = fmaf(w8, wp[8], a);
            sig[o] = a;
        }
    }

    // BN (inference, folded) + softmax over the 18 channels
    float mx = -3.4e38f;
#pragma unroll
    for (int o = 0; o < CO_; ++o) {
        const float inv = gamma[o] * rsqrtf(var[o] + 1e-5f);
        sig[o] = sig[o] * inv + (beta[o] - mean[o] * inv);
        mx = fmaxf(mx, sig[o]);
    }
    float sum = 0.f;
#pragma unroll
    for (int o = 0; o < CO_; ++o) {
        sig[o] = __expf(sig[o] - mx);
        sum += sig[o];
    }
    const float rs = 1.f / sum;
#pragma unroll
    for (int o = 0; o < CO_; ++o) sig[o] *= rs;

    // Pass 2: softmax-weighted aggregation of the same windows (L2 hits),
    // one output per channel. group g = c/32, kernel slot k = ki*3+kj.
#pragma unroll
    for (int g = 0; g < 2; ++g) {
        const float p0 = sig[g*9+0], p1 = sig[g*9+1], p2 = sig[g*9+2];
        const float p3 = sig[g*9+3], p4 = sig[g*9+4], p5 = sig[g*9+5];
        const float p6 = sig[g*9+6], p7 = sig[g*9+7], p8 = sig[g*9+8];
#pragma unroll 4
        for (int cc = 0; cc < 32; ++cc) {
            const int c = g*32 + cc;
            const float* __restrict__ xc = xn + c * (H_*W_);
            float acc =      xc[r0*W_ + c0] * p0;
            acc = fmaf(xc[r0*W_ + c1], p1, acc);
            acc = fmaf(xc[r0*W_ + c2], p2, acc);
            acc = fmaf(xc[r1*W_ + c0], p3, acc);
            acc = fmaf(xc[r1*W_ + c1], p4, acc);
            acc = fmaf(xc[r1*W_ + c2], p5, acc);
            acc = fmaf(xc[r2*W_ + c0], p6, acc);
            acc = fmaf(xc[r2*W_ + c1], p7, acc);
            acc = fmaf(xc[r2*W_ + c2], p8, acc);
            out[(((size_t)n*C_ + c)*HO_ + ho)*WO_ + wo] = acc;
        }
    }
}

extern "C" void kernel_launch(void* const* d_in, const int* in_sizes, int n_in,
                              void* d_out, int out_size, void* d_ws, size_t ws_size,
                              hipStream_t stream) {
    const float* x     = (const float*)d_in[0];
    const float* cw    = (const float*)d_in[1];
    const float* gamma = (const float*)d_in[2];
    const float* beta  = (const float*)d_in[3];
    const float* mean  = (const float*)d_in[4];
    const float* var   = (const float*)d_in[5];
    float* out = (float*)d_out;

    dim3 grid(16, 16);   // 16 ho-tiles (4 rows each) x 16 batch
    pasa_fused<<<grid, 256, 0, stream>>>(x, cw, gamma, beta, mean, var, out);
}

// Round 5
// 49.451 us; speedup vs baseline: 2.8434x; 2.8434x over previous
//
#include <hip/hip_runtime.h>

// Problem constants (from reference setup_inputs)
#define N_  16
#define C_  64
#define H_  128
#define W_  128
#define HO_ 64
#define WO_ 64
#define CO_ 18   // G*K*K = 2*3*3
#define NSP 8          // channel splits (= waves per block)
#define CPS (C_/NSP)   // 8 channels per split

__global__ __launch_bounds__(512, 8)
void pasa_fused2(const float* __restrict__ x,
                 const float* __restrict__ cw,
                 const float* __restrict__ gamma,
                 const float* __restrict__ beta,
                 const float* __restrict__ mean,
                 const float* __restrict__ var,
                 float* __restrict__ out)
{
    // partial conv logits: [split][o][wo] = 8*18*64*4 = 36864 B
    __shared__ float part[NSP][CO_][WO_];

    const int tid = threadIdx.x;
    const int wo  = tid & 63;          // lane -> output col
    const int sp  = tid >> 6;          // wave id = channel split, 0..7
    const int ho  = blockIdx.x;
    const int n   = blockIdx.y;

    // 3x3 window at input (2ho, 2wo), reflect pad=1 (only -1 reachable -> +1)
    int r0 = 2*ho - 1; if (r0 < 0) r0 = 1;
    const int r1 = 2*ho, r2 = 2*ho + 1;
    const int c1 = 2*wo, c2 = c1 + 1;  // c2 unused by name; via float2
    int c0 = c1 - 1; if (c0 < 0) c0 = 1;
    (void)c2;

    const float* __restrict__ xn = x + (size_t)n * (C_*H_*W_);

    float sig[CO_];
#pragma unroll
    for (int o = 0; o < CO_; ++o) sig[o] = 0.f;

    // Pass 1: partial conv over this wave's 8 channels -> 18 partial logits.
    // c is wave-uniform; readfirstlane forces weight addrs to SGPR (s_load).
#pragma unroll 2
    for (int j = 0; j < CPS; ++j) {
        const int c = __builtin_amdgcn_readfirstlane(sp * CPS + j);
        const float* __restrict__ xc = xn + c * (H_*W_);
        const float  w0  = xc[r0*W_ + c0];
        const float2 w12 = *(const float2*)(xc + r0*W_ + c1);  // 8B aligned
        const float  w3  = xc[r1*W_ + c0];
        const float2 w45 = *(const float2*)(xc + r1*W_ + c1);
        const float  w6  = xc[r2*W_ + c0];
        const float2 w78 = *(const float2*)(xc + r2*W_ + c1);
        const float* __restrict__ wc = cw + c * 9;
#pragma unroll
        for (int o = 0; o < CO_; ++o) {
            const float* __restrict__ q = wc + o * 576; // o-stride = 64*9
            float a = sig[o];
            a = fmaf(w0,    q[0], a);
            a = fmaf(w12.x, q[1], a);
            a = fmaf(w12.y, q[2], a);
            a = fmaf(w3,    q[3], a);
            a = fmaf(w45.x, q[4], a);
            a = fmaf(w45.y, q[5], a);
            a = fmaf(w6,    q[6], a);
            a = fmaf(w78.x, q[7], a);
            a = fmaf(w78.y, q[8], a);
            sig[o] = a;
        }
    }

    // Reduce the 8 partials (tree over sp; sp is wave-uniform -> no divergence)
#pragma unroll
    for (int o = 0; o < CO_; ++o) part[sp][o][wo] = sig[o];
    __syncthreads();
    if (sp < 4) {
#pragma unroll
        for (int o = 0; o < CO_; ++o) part[sp][o][wo] += part[sp+4][o][wo];
    }
    __syncthreads();
    if (sp < 2) {
#pragma unroll
        for (int o = 0; o < CO_; ++o) part[sp][o][wo] += part[sp+2][o][wo];
    }
    __syncthreads();
    if (sp == 0) {
#pragma unroll
        for (int o = 0; o < CO_; ++o) part[0][o][wo] += part[1][o][wo];
    }
    __syncthreads();

    // BN (folded) + softmax over 18 channels, redundant per thread (cheap)
    float mx = -3.4e38f;
#pragma unroll
    for (int o = 0; o < CO_; ++o) {
        const float inv = gamma[o] * rsqrtf(var[o] + 1e-5f);
        sig[o] = part[0][o][wo] * inv + (beta[o] - mean[o] * inv);
        mx = fmaxf(mx, sig[o]);
    }
    float sum = 0.f;
#pragma unroll
    for (int o = 0; o < CO_; ++o) { sig[o] = __expf(sig[o] - mx); sum += sig[o]; }
    const float rs = 1.f / sum;

    // Group-select with compile-time sig[] indices (g is wave-uniform)
    const int g = sp >> 2;   // channels sp*8..sp*8+7 all in group sp>>2
    float p[9];
    if (g == 0) {
#pragma unroll
        for (int k = 0; k < 9; ++k) p[k] = sig[k] * rs;
    } else {
#pragma unroll
        for (int k = 0; k < 9; ++k) p[k] = sig[9 + k] * rs;
    }

    // Pass 2: softmax-weighted aggregation for this wave's 8 channels.
    // Window values re-loaded (L1/L2-hot from pass 1).
#pragma unroll 2
    for (int j = 0; j < CPS; ++j) {
        const int c = __builtin_amdgcn_readfirstlane(sp * CPS + j);
        const float* __restrict__ xc = xn + c * (H_*W_);
        float acc = xc[r0*W_ + c0] * p[0];
        const float2 a12 = *(const float2*)(xc + r0*W_ + c1);
        acc = fmaf(a12.x, p[1], acc);
        acc = fmaf(a12.y, p[2], acc);
        acc = fmaf(xc[r1*W_ + c0], p[3], acc);
        const float2 a45 = *(const float2*)(xc + r1*W_ + c1);
        acc = fmaf(a45.x, p[4], acc);
        acc = fmaf(a45.y, p[5], acc);
        acc = fmaf(xc[r2*W_ + c0], p[6], acc);
        const float2 a78 = *(const float2*)(xc + r2*W_ + c1);
        acc = fmaf(a78.x, p[7], acc);
        acc = fmaf(a78.y, p[8], acc);
        out[(((size_t)n*C_ + c)*HO_ + ho)*WO_ + wo] = acc;
    }
}

extern "C" void kernel_launch(void* const* d_in, const int* in_sizes, int n_in,
                              void* d_out, int out_size, void* d_ws, size_t ws_size,
                              hipStream_t stream) {
    const float* x     = (const float*)d_in[0];
    const float* cw    = (const float*)d_in[1];
    const float* gamma = (const float*)d_in[2];
    const float* beta  = (const float*)d_in[3];
    const float* mean  = (const float*)d_in[4];
    const float* var   = (const float*)d_in[5];
    float* out = (float*)d_out;

    dim3 grid(HO_, N_);   // 64 ho-rows x 16 batch, 8 waves/block
    pasa_fused2<<<grid, 512, 0, stream>>>(x, cw, gamma, beta, mean, var, out);
}

// Round 6
// 43.924 us; speedup vs baseline: 3.2011x; 1.1258x over previous
//
#include <hip/hip_runtime.h>

// Problem constants (from reference setup_inputs)
#define N_  16
#define C_  64
#define H_  128
#define W_  128
#define HO_ 64
#define WO_ 64
#define CO_ 18   // G*K*K = 2*3*3
#define NSP 8          // channel splits (= waves per block)
#define CPS (C_/NSP)   // 8 channels per split

__global__ __launch_bounds__(512, 4)   // 128-VGPR class: room for wv[8][9]+sig[18]
void pasa_fused3(const float* __restrict__ x,
                 const float* __restrict__ cw,
                 const float* __restrict__ gamma,
                 const float* __restrict__ beta,
                 const float* __restrict__ mean,
                 const float* __restrict__ var,
                 float* __restrict__ out)
{
    // partial conv logits: [split][o][wo] = 8*18*64*4 = 36864 B
    __shared__ float part[NSP][CO_][WO_];

    const int tid = threadIdx.x;
    const int wo  = tid & 63;          // lane -> output col
    const int sp  = tid >> 6;          // wave id = channel split, 0..7
    // XCD-chunk swizzle: XCD = blockIdx-linear % 8 depends only on bx&7,
    // so map bx%8 -> ho-chunk: each XCD gets 8 contiguous ho rows
    // (adjacent rows share input rows -> L2 hits instead of 1.5x HBM fetch).
    const int bx  = blockIdx.x;
    const int ho  = ((bx & 7) << 3) | (bx >> 3);
    const int n   = blockIdx.y;

    // 3x3 window at input (2ho, 2wo), reflect pad=1 (only -1 reachable -> +1)
    int r0 = 2*ho - 1; if (r0 < 0) r0 = 1;
    const int r1 = 2*ho, r2 = 2*ho + 1;
    const int c1 = 2*wo;
    int c0 = c1 - 1; if (c0 < 0) c0 = 1;

    const float* __restrict__ xn = x + (size_t)n * (C_*H_*W_);

    // Load ALL window values for this wave's 8 channels into registers
    // (72 floats, compile-time indexed -> stays in VGPRs). One deep burst
    // of 48 load instrs; everything after runs out of registers.
    float wv[CPS][9];
#pragma unroll
    for (int j = 0; j < CPS; ++j) {
        const int c = sp * CPS + j;
        const float* __restrict__ xc = xn + c * (H_*W_);
        wv[j][0] = xc[r0*W_ + c0];
        float2 t = *(const float2*)(xc + r0*W_ + c1);   // 8B aligned
        wv[j][1] = t.x; wv[j][2] = t.y;
        wv[j][3] = xc[r1*W_ + c0];
        t = *(const float2*)(xc + r1*W_ + c1);
        wv[j][4] = t.x; wv[j][5] = t.y;
        wv[j][6] = xc[r2*W_ + c0];
        t = *(const float2*)(xc + r2*W_ + c1);
        wv[j][7] = t.x; wv[j][8] = t.y;
    }

    float sig[CO_];
#pragma unroll
    for (int o = 0; o < CO_; ++o) sig[o] = 0.f;

    // Pass 1: partial conv (8 channels -> 18 partial logits), all from regs.
    // Weight addresses are wave-uniform (readfirstlane) -> scalar loads.
#pragma unroll
    for (int j = 0; j < CPS; ++j) {
        const int c = __builtin_amdgcn_readfirstlane(sp * CPS + j);
        const float* __restrict__ wc = cw + c * 9;
#pragma unroll
        for (int o = 0; o < CO_; ++o) {
            const float* __restrict__ q = wc + o * 576; // o-stride = 64*9
            float a = sig[o];
#pragma unroll
            for (int k = 0; k < 9; ++k) a = fmaf(wv[j][k], q[k], a);
            sig[o] = a;
        }
    }

    // Reduce the 8 partials (tree over sp; sp is wave-uniform -> no divergence)
#pragma unroll
    for (int o = 0; o < CO_; ++o) part[sp][o][wo] = sig[o];
    __syncthreads();
    if (sp < 4) {
#pragma unroll
        for (int o = 0; o < CO_; ++o) part[sp][o][wo] += part[sp+4][o][wo];
    }
    __syncthreads();
    if (sp < 2) {
#pragma unroll
        for (int o = 0; o < CO_; ++o) part[sp][o][wo] += part[sp+2][o][wo];
    }
    __syncthreads();
    if (sp == 0) {
#pragma unroll
        for (int o = 0; o < CO_; ++o) part[0][o][wo] += part[1][o][wo];
    }
    __syncthreads();

    // BN (folded) + softmax over 18 channels, redundant per thread (cheap)
    float mx = -3.4e38f;
#pragma unroll
    for (int o = 0; o < CO_; ++o) {
        const float inv = gamma[o] * rsqrtf(var[o] + 1e-5f);
        sig[o] = part[0][o][wo] * inv + (beta[o] - mean[o] * inv);
        mx = fmaxf(mx, sig[o]);
    }
    float sum = 0.f;
#pragma unroll
    for (int o = 0; o < CO_; ++o) { sig[o] = __expf(sig[o] - mx); sum += sig[o]; }
    const float rs = 1.f / sum;

    // Group-select with compile-time sig[] indices (g is wave-uniform)
    const int g = sp >> 2;   // channels sp*8..sp*8+7 all in group sp>>2
    float p[9];
    if (g == 0) {
#pragma unroll
        for (int k = 0; k < 9; ++k) p[k] = sig[k] * rs;
    } else {
#pragma unroll
        for (int k = 0; k < 9; ++k) p[k] = sig[9 + k] * rs;
    }

    // Pass 2: softmax-weighted aggregation straight from registers (no loads).
#pragma unroll
    for (int j = 0; j < CPS; ++j) {
        const int c = sp * CPS + j;
        float acc = wv[j][0] * p[0];
#pragma unroll
        for (int k = 1; k < 9; ++k) acc = fmaf(wv[j][k], p[k], acc);
        out[(((size_t)n*C_ + c)*HO_ + ho)*WO_ + wo] = acc;
    }
}

extern "C" void kernel_launch(void* const* d_in, const int* in_sizes, int n_in,
                              void* d_out, int out_size, void* d_ws, size_t ws_size,
                              hipStream_t stream) {
    const float* x     = (const float*)d_in[0];
    const float* cw    = (const float*)d_in[1];
    const float* gamma = (const float*)d_in[2];
    const float* beta  = (const float*)d_in[3];
    const float* mean  = (const float*)d_in[4];
    const float* var   = (const float*)d_in[5];
    float* out = (float*)d_out;

    dim3 grid(HO_, N_);   // 64 ho-rows x 16 batch, 8 waves/block
    pasa_fused3<<<grid, 512, 0, stream>>>(x, cw, gamma, beta, mean, var, out);
}